// Round 11
// baseline (220.364 us; speedup 1.0000x reference)
//
#include <hip/hip_runtime.h>

#define N_NODES  100000
#define N_EDGES  1600000
#define HIDDEN   128
#define N_GRAPHS 2048
#define VOCAB    28
#define NB       196        // node buckets of 512 (196*512 = 100352)
#define CAP      10000      // per-bucket edge capacity (mean 8163, +20 sigma)
#define NBIN     1024       // binning blocks
#define EPB      1563       // edges per binning block (1024*1563 >= 1.6M)
#define EPT      7          // ceil(EPB/256)
#define NPREP    15         // 14 EW-chunk blocks + 1 bias block
#define CSTR     36         // lcnt stride: 16B-aligned, bank=(4*node+vix)%32
#define GCS      16         // gcursor stride (ints)
#define SMEMW    (EPB * 2 < VOCAB * HIDDEN ? VOCAB * HIDDEN : EPB * 2)

// ---------------------------------------------------------------------------
// k_binprep:
//   blocks 0..1023    : LDS multisplit of edges into NB dst-buckets
//   blocks 1024..1037 : EW chunk p (T=embed@w1_0 redundant in LDS, then chunk)
//   block  1038       : bc0 / wc1 / bc1
// packed edge: (dst&511)<<17 | src   (26 bits; vix gathered later in layerA)
// ---------------------------------------------------------------------------
__global__ __launch_bounds__(256) void k_binprep(const int* __restrict__ esrc,
                                                 const int* __restrict__ edst,
                                                 unsigned* __restrict__ binned,
                                                 int* __restrict__ gcursor,
                                                 const float* __restrict__ embed,
                                                 const float* __restrict__ w1_0,
                                                 const float* __restrict__ b1_0,
                                                 const float* __restrict__ w2_0,
                                                 const float* __restrict__ b2_0,
                                                 const float* __restrict__ w1_1,
                                                 const float* __restrict__ b1_1,
                                                 const float* __restrict__ w2_1,
                                                 const float* __restrict__ b2_1,
                                                 float* __restrict__ EW,
                                                 float* __restrict__ bc0,
                                                 float* __restrict__ wc1,
                                                 float* __restrict__ bc1) {
    __shared__ __align__(16) unsigned smem[SMEMW];
    __shared__ int hist[256];
    __shared__ int scanbuf[256];
    __shared__ int lbase[256];
    __shared__ int lcur[256];
    __shared__ int gbase[256];
    __shared__ int totS;

    const int tid = threadIdx.x;

    if (blockIdx.x >= NBIN) {
        const int p = blockIdx.x - NBIN;
        if (p < 14) {
            float* T = (float*)smem;
            for (int o = tid; o < VOCAB * HIDDEN; o += 256) {
                int i = o >> 7, j = o & 127;
                float s = 0.f;
#pragma unroll 8
                for (int k = 0; k < HIDDEN; ++k)
                    s += embed[i * HIDDEN + k] * w1_0[k * HIDDEN + j];
                T[o] = s;
            }
            __syncthreads();
            int o = p * 256 + tid;           // < 3584
            int i = o >> 7, j = o & 127;
            float s = 0.f;
#pragma unroll 8
            for (int k = 0; k < HIDDEN; ++k)
                s += T[i * HIDDEN + k] * w2_0[k * HIDDEN + j];
            EW[o] = s;
        } else {
            if (tid < 128) {
                float s = 0.f;
#pragma unroll 8
                for (int k = 0; k < HIDDEN; ++k)
                    s += b1_0[k] * w2_0[k * HIDDEN + tid];
                bc0[tid] = s + b2_0[tid];
                if (tid == 0) {
                    float q = 0.f;
                    for (int k = 0; k < HIDDEN; ++k) q += b1_1[k] * w2_1[k];
                    bc1[0] = q + b2_1[0];
                }
            } else {
                int i = tid - 128;
                float s = 0.f;
#pragma unroll 8
                for (int k = 0; k < HIDDEN; ++k)
                    s += w1_1[i * HIDDEN + k] * w2_1[k];
                wc1[i] = s;
            }
        }
        return;
    }

    // ---- bin path
    unsigned* stage = smem;
    int*      tgt   = (int*)(smem + EPB);

    hist[tid] = 0;
    lcur[tid] = 0;
    __syncthreads();

    unsigned mypk[EPT];
    short    myb[EPT];
#pragma unroll
    for (int i = 0; i < EPT; ++i) {
        int idx = i * 256 + tid;
        int e   = blockIdx.x * EPB + idx;
        myb[i] = -1;
        if (idx < EPB && e < N_EDGES) {
            int dst = edst[e];
            int src = esrc[e];
            int b   = dst >> 9;
            int dl  = dst & 511;
            mypk[i] = ((unsigned)dl << 17) | (unsigned)src;
            myb[i]  = (short)b;
            atomicAdd(&hist[b], 1);
        }
    }
    __syncthreads();

    int v = hist[tid];
    scanbuf[tid] = v;
    __syncthreads();
    for (int off = 1; off < 256; off <<= 1) {
        int x = (tid >= off) ? scanbuf[tid - off] : 0;
        __syncthreads();
        scanbuf[tid] += x;
        __syncthreads();
    }
    lbase[tid] = scanbuf[tid] - v;
    if (tid == 255) totS = scanbuf[255];
    if (tid < NB) gbase[tid] = (v > 0) ? atomicAdd(&gcursor[tid * GCS], v) : 0;
    __syncthreads();

#pragma unroll
    for (int i = 0; i < EPT; ++i) {
        if (myb[i] >= 0) {
            int b   = myb[i];
            int pos = lbase[b] + atomicAdd(&lcur[b], 1);
            stage[pos] = mypk[i];
            tgt[pos]   = b * CAP + gbase[b] + (pos - lbase[b]);
        }
    }
    __syncthreads();

    const int tot = totS;
    for (int i = tid; i < tot; i += 256)
        binned[tgt[i]] = stage[i];
}

// ---------------------------------------------------------------------------
// k_layerA: per (bucket b, half h) block of 256 nodes:
//   1) float vocab histogram in LDS; vix gathered here (x_idx L1/L2-resident)
//   2) self-term (1+eps0) folded in (non-atomic per-node add)
//   3) lane = feat pair {lane, lane+64}; EW resident in 56 VGPRs; per node:
//      7 wave-uniform ds_read_b128 + 56 FMA + relu-dot + butterfly reduce.
// ---------------------------------------------------------------------------
__global__ __launch_bounds__(256) void k_layerA(const unsigned* __restrict__ binned,
                                                const int* __restrict__ gcursor,
                                                const int* __restrict__ x_idx,
                                                const float* __restrict__ EW,
                                                const float* __restrict__ bc0,
                                                const float* __restrict__ wc1,
                                                const float* __restrict__ eps0,
                                                float* __restrict__ d) {
    __shared__ __align__(16) float lcnt[256 * CSTR];   // 36 KB

    const int tid = threadIdx.x;
    const int b   = blockIdx.x >> 1;
    const int h   = blockIdx.x & 1;

    for (int i = tid; i < 256 * CSTR; i += 256) lcnt[i] = 0.f;
    __syncthreads();

    const int cnt = gcursor[b * GCS];
    const unsigned* bp = binned + (size_t)b * CAP;
    for (int i = tid; i < cnt; i += 256) {
        unsigned pk = bp[i];
        int dl = pk >> 17;
        if ((dl >> 8) == h) {
            int vix = x_idx[pk & 0x1FFFFu];
            atomicAdd(&lcnt[(dl & 255) * CSTR + vix], 1.0f);
        }
    }
    __syncthreads();

    const int n_self = b * 512 + h * 256 + tid;
    if (n_self < N_NODES)
        lcnt[tid * CSTR + x_idx[n_self]] += 1.0f + eps0[0];
    __syncthreads();

    const int wave = tid >> 6, lane = tid & 63;

    float ew0[VOCAB], ew1[VOCAB];
#pragma unroll
    for (int v = 0; v < VOCAB; ++v) {
        ew0[v] = EW[v * HIDDEN + lane];
        ew1[v] = EW[v * HIDDEN + lane + 64];
    }
    const float blo = bc0[lane], bhi = bc0[lane + 64];
    const float wlo = wc1[lane], whi = wc1[lane + 64];

    const int nbl = wave * 64;
    float dmine = 0.f;
#pragma unroll 1
    for (int j = 0; j < 64; ++j) {
        const float4* cp = reinterpret_cast<const float4*>(&lcnt[(nbl + j) * CSTR]);
        float4 c0 = cp[0], c1 = cp[1], c2 = cp[2], c3 = cp[3];
        float4 c4 = cp[4], c5 = cp[5], c6 = cp[6];
        float a0 = blo, a1 = bhi;
#define FM(cc, v) a0 = fmaf(cc, ew0[v], a0); a1 = fmaf(cc, ew1[v], a1);
        FM(c0.x, 0)  FM(c0.y, 1)  FM(c0.z, 2)  FM(c0.w, 3)
        FM(c1.x, 4)  FM(c1.y, 5)  FM(c1.z, 6)  FM(c1.w, 7)
        FM(c2.x, 8)  FM(c2.y, 9)  FM(c2.z, 10) FM(c2.w, 11)
        FM(c3.x, 12) FM(c3.y, 13) FM(c3.z, 14) FM(c3.w, 15)
        FM(c4.x, 16) FM(c4.y, 17) FM(c4.z, 18) FM(c4.w, 19)
        FM(c5.x, 20) FM(c5.y, 21) FM(c5.z, 22) FM(c5.w, 23)
        FM(c6.x, 24) FM(c6.y, 25) FM(c6.z, 26) FM(c6.w, 27)
#undef FM
        float t = fmaxf(a0, 0.f) * wlo + fmaxf(a1, 0.f) * whi;
#pragma unroll
        for (int off = 32; off >= 1; off >>= 1) t += __shfl_xor(t, off, 64);
        if (lane == j) dmine = t;
    }
    const int n = b * 512 + h * 256 + nbl + lane;
    if (n < N_NODES) d[n] = dmine;
}

// ---------------------------------------------------------------------------
// k_B2: per (bucket b, half h): racc[256] in LDS from d[src] gathers over the
// bucket's edges (filtered by half). Fused output: x write + batch segment-sum.
// ---------------------------------------------------------------------------
__global__ __launch_bounds__(256) void k_B2(const unsigned* __restrict__ binned,
                                            const int* __restrict__ gcursor,
                                            const float* __restrict__ d,
                                            const int* __restrict__ batch,
                                            const float* __restrict__ eps1,
                                            const float* __restrict__ bc1,
                                            float* __restrict__ out) {
    __shared__ float racc[256];
    __shared__ float gacc[N_GRAPHS];

    const int tid = threadIdx.x;
    const int b   = blockIdx.x >> 1;
    const int h   = blockIdx.x & 1;
    const int n0  = b * 512 + h * 256;
    if (n0 >= N_NODES) return;                  // empty upper half of last bucket
    const int nlast = min(n0 + 255, N_NODES - 1);

    racc[tid] = 0.f;
    const int g0 = batch[n0];
    const int g1 = batch[nlast];
    for (int g = g0 + tid; g <= g1; g += 256) gacc[g] = 0.f;
    __syncthreads();

    const int cnt = gcursor[b * GCS];
    const unsigned* bp = binned + (size_t)b * CAP;
    for (int i = tid; i < cnt; i += 256) {
        unsigned pk = bp[i];
        int dl = pk >> 17;
        if ((dl >> 8) == h)
            atomicAdd(&racc[dl & 255], d[pk & 0x1FFFFu]);
    }
    __syncthreads();

    const int n = n0 + tid;
    if (n < N_NODES) {
        float r = (1.0f + eps1[0]) * d[n] + racc[tid] + bc1[0];
        out[N_GRAPHS + n] = r;
        atomicAdd(&gacc[batch[n]], r);
    }
    __syncthreads();
    for (int g = g0 + tid; g <= g1; g += 256) {
        float v = gacc[g];
        if (v != 0.f) atomicAdd(&out[g], v);
    }
}

// ---------------------------------------------------------------------------
extern "C" void kernel_launch(void* const* d_in, const int* in_sizes, int n_in,
                              void* d_out, int out_size, void* d_ws, size_t ws_size,
                              hipStream_t stream) {
    const int*   x_idx = (const int*)d_in[0];
    const int*   esrc  = (const int*)d_in[1];
    const int*   edst  = (const int*)d_in[2];
    const int*   batch = (const int*)d_in[3];
    const float* embed = (const float*)d_in[4];
    const float* eps0  = (const float*)d_in[5];
    const float* w1_0  = (const float*)d_in[6];
    const float* b1_0  = (const float*)d_in[7];
    const float* w2_0  = (const float*)d_in[8];
    const float* b2_0  = (const float*)d_in[9];
    const float* eps1  = (const float*)d_in[10];
    const float* w1_1  = (const float*)d_in[11];
    const float* b1_1  = (const float*)d_in[12];
    const float* w2_1  = (const float*)d_in[13];
    const float* b2_1  = (const float*)d_in[14];

    float* out = (float*)d_out;

    // workspace: [gcursor(256*GCS) | binned(NB*CAP) | d(N) | bc0 | wc1 | bc1 | EW]
    int*      gcursor = (int*)d_ws;                               // 256*GCS
    unsigned* binned  = (unsigned*)(gcursor + 256 * GCS);         // NB*CAP
    float*    d       = (float*)(binned + (size_t)NB * CAP);      // N
    float*    bc0     = d + N_NODES;                              // 128
    float*    wc1     = bc0 + HIDDEN;                             // 128
    float*    bc1     = wc1 + HIDDEN;                             // 1
    float*    EW      = bc1 + 1;                                  // 28*128

    hipMemsetAsync(out, 0, N_GRAPHS * sizeof(float), stream);
    hipMemsetAsync(gcursor, 0, 256 * GCS * sizeof(int), stream);

    // bin (blocks 0..1023) + weight folding (blocks 1024..1038)
    k_binprep<<<NBIN + NPREP, 256, 0, stream>>>(esrc, edst, binned, gcursor,
                                                embed, w1_0, b1_0, w2_0, b2_0,
                                                w1_1, b1_1, w2_1, b2_1,
                                                EW, bc0, wc1, bc1);

    // layer 0 (+dot wc1): register-resident EW, float counts, vix gathered here
    k_layerA<<<NB * 2, 256, 0, stream>>>(binned, gcursor, x_idx, EW, bc0, wc1, eps0, d);

    // layer 1 aggregation in LDS + fused outputs (bucket halves)
    k_B2<<<NB * 2, 256, 0, stream>>>(binned, gcursor, d, batch, eps1, bc1, out);
}

// Round 12
// 198.676 us; speedup vs baseline: 1.1092x; 1.1092x over previous
//
#include <hip/hip_runtime.h>

#define N_NODES  100000
#define N_EDGES  1600000
#define HIDDEN   128
#define N_GRAPHS 2048
#define VOCAB    28
#define NB       196        // node buckets of 512 (196*512 = 100352)
#define CAP      10000      // per-bucket edge capacity (mean 8163, +20 sigma)
#define NBIN     256        // binning blocks (EPB 6250 -> ~32-word runs per bucket)
#define EPB      6250       // edges per binning block (256 * 6250 = 1.6M exact)
#define EPT      25         // EPB / 256 (rounded up)
#define NPREP    15         // 14 EW-chunk blocks + 1 bias block
#define CSTR     36         // lcnt stride: 16B-aligned, bank=(4*node+vix)%32 spread
#define GCS      16         // gcursor stride (ints): one cursor per 64B line
#define SMEMW    (EPB * 2)  // stage+tgt (also covers T: 3584 < EPB*2)

// ---------------------------------------------------------------------------
// k_binprep:
//   blocks 0..255   : LDS multisplit of edges into NB dst-buckets
//                     (EPB=6250 -> ~32-consecutive-word runs per bucket in the
//                      scattered write phase; r9-r11 showed smaller runs
//                      fragment stores and regress)
//   blocks 256..269 : EW chunk p: T = embed@w1_0 (redundant, LDS), then
//                     EW[p*256 .. p*256+255] = (T @ w2_0) chunk
//   block  270      : bc0 = b1_0@w2_0 + b2_0 ; wc1 = w1_1@w2_1 ; bc1
// packed edge: (dst&511)<<22 | x_idx[src]<<17 | src   (31 bits)
// ---------------------------------------------------------------------------
__global__ __launch_bounds__(256) void k_binprep(const int* __restrict__ esrc,
                                                 const int* __restrict__ edst,
                                                 const int* __restrict__ x_idx,
                                                 unsigned* __restrict__ binned,
                                                 int* __restrict__ gcursor,
                                                 const float* __restrict__ embed,
                                                 const float* __restrict__ w1_0,
                                                 const float* __restrict__ b1_0,
                                                 const float* __restrict__ w2_0,
                                                 const float* __restrict__ b2_0,
                                                 const float* __restrict__ w1_1,
                                                 const float* __restrict__ b1_1,
                                                 const float* __restrict__ w2_1,
                                                 const float* __restrict__ b2_1,
                                                 float* __restrict__ EW,
                                                 float* __restrict__ bc0,
                                                 float* __restrict__ wc1,
                                                 float* __restrict__ bc1) {
    __shared__ __align__(16) unsigned smem[SMEMW];   // 50 KB: stage+tgt / T overlay
    __shared__ int hist[256];
    __shared__ int scanbuf[256];
    __shared__ int lbase[256];
    __shared__ int lcur[256];
    __shared__ int gbase[256];

    const int tid = threadIdx.x;

    if (blockIdx.x >= NBIN) {
        const int p = blockIdx.x - NBIN;
        if (p < 14) {
            float* T = (float*)smem;
            for (int o = tid; o < VOCAB * HIDDEN; o += 256) {
                int i = o >> 7, j = o & 127;
                float s = 0.f;
#pragma unroll 8
                for (int k = 0; k < HIDDEN; ++k)
                    s += embed[i * HIDDEN + k] * w1_0[k * HIDDEN + j];
                T[o] = s;
            }
            __syncthreads();
            int o = p * 256 + tid;           // < 3584
            int i = o >> 7, j = o & 127;
            float s = 0.f;
#pragma unroll 8
            for (int k = 0; k < HIDDEN; ++k)
                s += T[i * HIDDEN + k] * w2_0[k * HIDDEN + j];
            EW[o] = s;
        } else {
            if (tid < 128) {
                float s = 0.f;
#pragma unroll 8
                for (int k = 0; k < HIDDEN; ++k)
                    s += b1_0[k] * w2_0[k * HIDDEN + tid];
                bc0[tid] = s + b2_0[tid];
                if (tid == 0) {
                    float q = 0.f;
                    for (int k = 0; k < HIDDEN; ++k) q += b1_1[k] * w2_1[k];
                    bc1[0] = q + b2_1[0];
                }
            } else {
                int i = tid - 128;
                float s = 0.f;
#pragma unroll 8
                for (int k = 0; k < HIDDEN; ++k)
                    s += w1_1[i * HIDDEN + k] * w2_1[k];
                wc1[i] = s;
            }
        }
        return;
    }

    // ---- bin path
    unsigned* stage = smem;
    int*      tgt   = (int*)(smem + EPB);

    hist[tid] = 0;
    lcur[tid] = 0;
    __syncthreads();

    unsigned mypk[EPT];
    short    myb[EPT];
#pragma unroll
    for (int i = 0; i < EPT; ++i) {
        int idx = i * 256 + tid;
        myb[i] = -1;
        if (idx < EPB) {
            int e   = blockIdx.x * EPB + idx;
            int dst = edst[e];
            int src = esrc[e];
            int b   = dst >> 9;
            int dl  = dst & 511;
            int vix = x_idx[src];
            mypk[i] = ((unsigned)dl << 22) | ((unsigned)vix << 17) | (unsigned)src;
            myb[i]  = (short)b;
            atomicAdd(&hist[b], 1);
        }
    }
    __syncthreads();

    int v = hist[tid];
    scanbuf[tid] = v;
    __syncthreads();
    for (int off = 1; off < 256; off <<= 1) {
        int x = (tid >= off) ? scanbuf[tid - off] : 0;
        __syncthreads();
        scanbuf[tid] += x;
        __syncthreads();
    }
    lbase[tid] = scanbuf[tid] - v;
    if (tid < NB) gbase[tid] = (v > 0) ? atomicAdd(&gcursor[tid * GCS], v) : 0;
    __syncthreads();

#pragma unroll
    for (int i = 0; i < EPT; ++i) {
        if (myb[i] >= 0) {
            int b   = myb[i];
            int pos = lbase[b] + atomicAdd(&lcur[b], 1);
            stage[pos] = mypk[i];
            tgt[pos]   = b * CAP + gbase[b] + (pos - lbase[b]);
        }
    }
    __syncthreads();

    for (int i = tid; i < EPB; i += 256)
        binned[tgt[i]] = stage[i];
}

// ---------------------------------------------------------------------------
// k_layerA: per (bucket b, half h) block of 256 nodes:
//   1) float vocab histogram in LDS (stride 36: bank=(4*node+vix)%32, spread)
//   2) self-term (1+eps0) folded in (non-atomic per-node add)
//   3) lane = feat pair {lane, lane+64}; EW resident in 56 VGPRs; per node:
//      7 wave-uniform ds_read_b128 + 56 FMA + relu-dot + butterfly reduce.
// ---------------------------------------------------------------------------
__global__ __launch_bounds__(256) void k_layerA(const unsigned* __restrict__ binned,
                                                const int* __restrict__ gcursor,
                                                const int* __restrict__ x_idx,
                                                const float* __restrict__ EW,
                                                const float* __restrict__ bc0,
                                                const float* __restrict__ wc1,
                                                const float* __restrict__ eps0,
                                                float* __restrict__ d) {
    __shared__ __align__(16) float lcnt[256 * CSTR];   // 36 KB

    const int tid = threadIdx.x;
    const int b   = blockIdx.x >> 1;
    const int h   = blockIdx.x & 1;

    for (int i = tid; i < 256 * CSTR; i += 256) lcnt[i] = 0.f;
    __syncthreads();

    const int cnt = gcursor[b * GCS];
    const unsigned* bp = binned + (size_t)b * CAP;
    for (int i = tid; i < cnt; i += 256) {
        unsigned pk = bp[i];
        int dl = pk >> 22;
        if ((dl >> 8) == h)
            atomicAdd(&lcnt[(dl & 255) * CSTR + ((pk >> 17) & 31)], 1.0f);
    }
    __syncthreads();

    const int n_self = b * 512 + h * 256 + tid;
    if (n_self < N_NODES)
        lcnt[tid * CSTR + x_idx[n_self]] += 1.0f + eps0[0];
    __syncthreads();

    const int wave = tid >> 6, lane = tid & 63;

    float ew0[VOCAB], ew1[VOCAB];
#pragma unroll
    for (int v = 0; v < VOCAB; ++v) {
        ew0[v] = EW[v * HIDDEN + lane];
        ew1[v] = EW[v * HIDDEN + lane + 64];
    }
    const float blo = bc0[lane], bhi = bc0[lane + 64];
    const float wlo = wc1[lane], whi = wc1[lane + 64];

    const int nbl = wave * 64;
    float dmine = 0.f;
#pragma unroll 1
    for (int j = 0; j < 64; ++j) {
        const float4* cp = reinterpret_cast<const float4*>(&lcnt[(nbl + j) * CSTR]);
        float4 c0 = cp[0], c1 = cp[1], c2 = cp[2], c3 = cp[3];
        float4 c4 = cp[4], c5 = cp[5], c6 = cp[6];
        float a0 = blo, a1 = bhi;
#define FM(cc, v) a0 = fmaf(cc, ew0[v], a0); a1 = fmaf(cc, ew1[v], a1);
        FM(c0.x, 0)  FM(c0.y, 1)  FM(c0.z, 2)  FM(c0.w, 3)
        FM(c1.x, 4)  FM(c1.y, 5)  FM(c1.z, 6)  FM(c1.w, 7)
        FM(c2.x, 8)  FM(c2.y, 9)  FM(c2.z, 10) FM(c2.w, 11)
        FM(c3.x, 12) FM(c3.y, 13) FM(c3.z, 14) FM(c3.w, 15)
        FM(c4.x, 16) FM(c4.y, 17) FM(c4.z, 18) FM(c4.w, 19)
        FM(c5.x, 20) FM(c5.y, 21) FM(c5.z, 22) FM(c5.w, 23)
        FM(c6.x, 24) FM(c6.y, 25) FM(c6.z, 26) FM(c6.w, 27)
#undef FM
        float t = fmaxf(a0, 0.f) * wlo + fmaxf(a1, 0.f) * whi;
#pragma unroll
        for (int off = 32; off >= 1; off >>= 1) t += __shfl_xor(t, off, 64);
        if (lane == j) dmine = t;
    }
    const int n = b * 512 + h * 256 + nbl + lane;
    if (n < N_NODES) d[n] = dmine;
}

// ---------------------------------------------------------------------------
// k_B2: per bucket: racc[512] in LDS (ds float atomics) from d[src] gathers
// (d = 400 KB, L2-resident). Fused output: x write + batch segment-sum.
// ---------------------------------------------------------------------------
__global__ __launch_bounds__(512) void k_B2(const unsigned* __restrict__ binned,
                                            const int* __restrict__ gcursor,
                                            const float* __restrict__ d,
                                            const int* __restrict__ batch,
                                            const float* __restrict__ eps1,
                                            const float* __restrict__ bc1,
                                            float* __restrict__ out) {
    __shared__ float racc[512];
    __shared__ float gacc[N_GRAPHS];

    const int tid = threadIdx.x;
    const int b   = blockIdx.x;
    const int n0  = b * 512;
    const int nlast = min(n0 + 511, N_NODES - 1);

    racc[tid] = 0.f;
    const int g0 = batch[n0];
    const int g1 = batch[nlast];
    for (int g = g0 + tid; g <= g1; g += 512) gacc[g] = 0.f;
    __syncthreads();

    const int cnt = gcursor[b * GCS];
    const unsigned* bp = binned + (size_t)b * CAP;
    for (int i = tid; i < cnt; i += 512) {
        unsigned pk = bp[i];
        atomicAdd(&racc[pk >> 22], d[pk & 0x1FFFFu]);
    }
    __syncthreads();

    int n = n0 + tid;
    if (n < N_NODES) {
        float r = (1.0f + eps1[0]) * d[n] + racc[tid] + bc1[0];
        out[N_GRAPHS + n] = r;
        atomicAdd(&gacc[batch[n]], r);
    }
    __syncthreads();
    for (int g = g0 + tid; g <= g1; g += 512) {
        float v = gacc[g];
        if (v != 0.f) atomicAdd(&out[g], v);
    }
}

// ---------------------------------------------------------------------------
extern "C" void kernel_launch(void* const* d_in, const int* in_sizes, int n_in,
                              void* d_out, int out_size, void* d_ws, size_t ws_size,
                              hipStream_t stream) {
    const int*   x_idx = (const int*)d_in[0];
    const int*   esrc  = (const int*)d_in[1];
    const int*   edst  = (const int*)d_in[2];
    const int*   batch = (const int*)d_in[3];
    const float* embed = (const float*)d_in[4];
    const float* eps0  = (const float*)d_in[5];
    const float* w1_0  = (const float*)d_in[6];
    const float* b1_0  = (const float*)d_in[7];
    const float* w2_0  = (const float*)d_in[8];
    const float* b2_0  = (const float*)d_in[9];
    const float* eps1  = (const float*)d_in[10];
    const float* w1_1  = (const float*)d_in[11];
    const float* b1_1  = (const float*)d_in[12];
    const float* w2_1  = (const float*)d_in[13];
    const float* b2_1  = (const float*)d_in[14];

    float* out = (float*)d_out;

    // workspace: [gcursor(256*GCS) | binned(NB*CAP) | d(N) | bc0 | wc1 | bc1 | EW]
    int*      gcursor = (int*)d_ws;                               // 256*GCS
    unsigned* binned  = (unsigned*)(gcursor + 256 * GCS);         // NB*CAP
    float*    d       = (float*)(binned + (size_t)NB * CAP);      // N
    float*    bc0     = d + N_NODES;                              // 128
    float*    wc1     = bc0 + HIDDEN;                             // 128
    float*    bc1     = wc1 + HIDDEN;                             // 1
    float*    EW      = bc1 + 1;                                  // 28*128

    hipMemsetAsync(out, 0, N_GRAPHS * sizeof(float), stream);
    hipMemsetAsync(gcursor, 0, 256 * GCS * sizeof(int), stream);

    // bin (blocks 0..255, 32-word runs) + weight folding (blocks 256..270)
    k_binprep<<<NBIN + NPREP, 256, 0, stream>>>(esrc, edst, x_idx, binned, gcursor,
                                                embed, w1_0, b1_0, w2_0, b2_0,
                                                w1_1, b1_1, w2_1, b2_1,
                                                EW, bc0, wc1, bc1);

    // layer 0 (+dot wc1): register-resident EW, float counts
    k_layerA<<<NB * 2, 256, 0, stream>>>(binned, gcursor, x_idx, EW, bc0, wc1, eps0, d);

    // layer 1 aggregation in LDS + fused outputs
    k_B2<<<NB, 512, 0, stream>>>(binned, gcursor, d, batch, eps1, bc1, out);
}